// Round 6
// baseline (291.351 us; speedup 1.0000x reference)
//
#include <hip/hip_runtime.h>
#include <math.h>

#define N_NODES 100000
#define N_EDGES 1600000
#define NB 391              // dst buckets (d>>8), 256 nodes each
#define MROWS 100096        // 782*128, padded row count for guard-free tiles
#define CH 3200             // edges per bucket_scatter block -> 500 blocks

typedef __attribute__((ext_vector_type(8))) short short8;  // 8 bf16 = 4 VGPRs
typedef __attribute__((ext_vector_type(4))) float f32x4;
typedef __attribute__((ext_vector_type(2))) float f32x2;

__device__ __forceinline__ short f2b(float f) {            // fp32 -> bf16 RNE
    unsigned u = __float_as_uint(f);
    unsigned r = (u + 0x7FFFu + ((u >> 16) & 1u)) >> 16;
    return (short)r;
}
__device__ __forceinline__ unsigned pk2(float a, float b) {
    return (unsigned)(unsigned short)f2b(a) | ((unsigned)(unsigned short)f2b(b) << 16);
}
// f32 -> fp8 e4m3 (OCP), single byte
__device__ __forceinline__ unsigned char f2q(float v) {
    return (unsigned char)(__builtin_amdgcn_cvt_pk_fp8_f32(v, 0.f, 0, false) & 0xFF);
}
// accumulate 4 fp8 (one uint) into a[0..1] as packed f32x2 (v_pk_add_f32)
__device__ __forceinline__ void acc2(f32x2* a, unsigned u) {
    a[0] += __builtin_amdgcn_cvt_pk_f32_fp8((int)u, false);
    a[1] += __builtin_amdgcn_cvt_pk_f32_fp8((int)u, true);
}
// accumulate 16 fp8 (one uint4) into a[0..7]
__device__ __forceinline__ void acc16(f32x2* a, uint4 u) {
    acc2(a + 0, u.x); acc2(a + 2, u.y); acc2(a + 4, u.z); acc2(a + 6, u.w);
}

// pack 8 fp32 -> 8 bf16 (truncate; 1 v_perm per 2 elems)
__device__ __forceinline__ short8 pack8t(const float* __restrict__ p) {
    float4 v0 = ((const float4*)p)[0];
    float4 v1 = ((const float4*)p)[1];
    union { unsigned u[4]; short8 s; } r;
    r.u[0] = __builtin_amdgcn_perm(__float_as_uint(v0.y), __float_as_uint(v0.x), 0x07060302u);
    r.u[1] = __builtin_amdgcn_perm(__float_as_uint(v0.w), __float_as_uint(v0.z), 0x07060302u);
    r.u[2] = __builtin_amdgcn_perm(__float_as_uint(v1.y), __float_as_uint(v1.x), 0x07060302u);
    r.u[3] = __builtin_amdgcn_perm(__float_as_uint(v1.w), __float_as_uint(v1.z), 0x07060302u);
    return r.s;
}

// ---------- init: bcnt zeros ----------
__global__ __launch_bounds__(512) void init_misc(int* __restrict__ bcnt) {
    int t = threadIdx.x;
    if (t < NB) bcnt[t] = 0;
}

// ---------- bucket histogram (LDS-staged) ----------
__global__ __launch_bounds__(256) void bucket_count(const int* __restrict__ dst,
                                                    int* __restrict__ bcnt) {
    __shared__ int h[NB];
    int t = threadIdx.x;
    for (int i = t; i < NB; i += 256) h[i] = 0;
    __syncthreads();
    for (int e = blockIdx.x * 256 + t; e < N_EDGES; e += gridDim.x * 256)
        atomicAdd(&h[dst[e] >> 8], 1);
    __syncthreads();
    for (int i = t; i < NB; i += 256)
        if (h[i]) atomicAdd(&bcnt[i], h[i]);
}

// ---------- bucket-level exclusive scan (one block) ----------
__global__ __launch_bounds__(512) void bucket_scan(const int* __restrict__ bcnt,
                                                   int* __restrict__ boffs,
                                                   int* __restrict__ bcur) {
    __shared__ int s[512];
    int t = threadIdx.x;
    int v = (t < NB) ? bcnt[t] : 0;
    s[t] = v;
    __syncthreads();
    for (int off = 1; off < 512; off <<= 1) {
        int u = (t >= off) ? s[t - off] : 0;
        __syncthreads();
        s[t] += u;
        __syncthreads();
    }
    if (t < NB) {
        int ex = s[t] - v;
        boffs[t] = ex;
        bcur[t] = ex;
    }
    if (t == 0) boffs[NB] = N_EDGES;
}

// ---------- scatter edges into bucket-grouped packed list ----------
// packed word: (d&255)<<24 | src   (src < 2^24)
__global__ __launch_bounds__(256) void bucket_scatter(const int* __restrict__ src,
                                                      const int* __restrict__ dst,
                                                      int* __restrict__ bcur,
                                                      unsigned* __restrict__ pairs) {
    __shared__ unsigned lw[CH];
    __shared__ short lb[CH];
    __shared__ int cnt[NB];
    __shared__ int lstart[NB];
    int t = threadIdx.x;
    int e0 = blockIdx.x * CH;
    int n = min(CH, N_EDGES - e0);
    for (int i = t; i < NB; i += 256) cnt[i] = 0;
    __syncthreads();
    for (int i = t; i < n; i += 256) {
        int s = src[e0 + i], d = dst[e0 + i];
        lw[i] = ((unsigned)(d & 255) << 24) | (unsigned)s;
        int b = d >> 8;
        lb[i] = (short)b;
        atomicAdd(&cnt[b], 1);
    }
    __syncthreads();
    for (int b = t; b < NB; b += 256) {
        int c = cnt[b];
        lstart[b] = c ? atomicAdd(&bcur[b], c) : 0;
        cnt[b] = 0;  // reuse as local cursor
    }
    __syncthreads();
    for (int i = t; i < n; i += 256) {
        int b = lb[i];
        int lo = atomicAdd(&cnt[b], 1);
        pairs[lstart[b] + lo] = lw[i];
    }
}

// ---------- bucket-local CSR fill; self-loop at slot 0; NO padding ----------
__global__ __launch_bounds__(256) void csr_fill_bucket(const unsigned* __restrict__ pairs,
                                                       const int* __restrict__ boffs,
                                                       int2* __restrict__ rinfo,
                                                       float* __restrict__ dinv,
                                                       int* __restrict__ srcs) {
    __shared__ int lcnt[256];
    __shared__ int ls[256];
    int t = threadIdx.x, b = blockIdx.x, base = b << 8;
    lcnt[t] = 0;
    __syncthreads();
    int lo_e = boffs[b], hi_e = boffs[b + 1];
    for (int i = lo_e + t; i < hi_e; i += 256)
        atomicAdd(&lcnt[pairs[i] >> 24], 1);
    __syncthreads();
    int c = lcnt[t];
    int len = c + 1;                   // self-loop included, exact length
    ls[t] = len;
    __syncthreads();
    for (int off = 1; off < 256; off <<= 1) {
        int u = (t >= off) ? ls[t - off] : 0;
        __syncthreads();
        ls[t] += u;
        __syncthreads();
    }
    int rp = lo_e + base + ls[t] - len;   // edges-before + selves-before
    int node = base + t;
    if (node < N_NODES) {
        rinfo[node] = make_int2(rp, rp + len);
        dinv[node] = rsqrtf((float)len);
        srcs[rp] = node;               // folded self-loop at slot 0
    }
    __syncthreads();
    lcnt[t] = rp + 1;                  // reuse as global cursor (slot 0 = self)
    __syncthreads();
    for (int i = lo_e + t; i < hi_e; i += 256) {
        unsigned p = pairs[i];
        int li = p >> 24;
        int pos = atomicAdd(&lcnt[li], 1);
        srcs[pos] = (int)(p & 0xFFFFFFu);
    }
}

// ---------- W1 [128][128] + W2 [128][64] fp32 -> Wt [N][128] bf16 ----------
__global__ __launch_bounds__(256) void convert_w(const float* __restrict__ W1,
                                                 const float* __restrict__ W2,
                                                 short* __restrict__ w1h,
                                                 short* __restrict__ w2h) {
    int id = blockIdx.x * 256 + threadIdx.x;
    if (id < 128 * 128) {
        int n = id >> 7, k = id & 127;
        w1h[id] = f2b(W1[k * 128 + n]);
    } else if (id < 128 * 128 + 64 * 128) {
        int j = id - 128 * 128;
        int n = j >> 7, k = j & 127;
        w2h[j] = f2b(W2[k * 64 + n]);
    }
}

// ---------- layer-1 GEMM: Y1 = fp8((X @ W1) * dinv), CHUNK-MAJOR [4][MROWS][32] ----------
__global__ __launch_bounds__(512) void gemm1_mfma(const float* __restrict__ X,
                                                  const short* __restrict__ Wt,
                                                  const float* __restrict__ dinv,
                                                  unsigned char* __restrict__ Yf) {
    __shared__ short Ws[128 * 128];   // 32 KB
    const int t = threadIdx.x;
    for (int i = t * 8; i < 128 * 128; i += 512 * 8)
        *(short8*)(Ws + i) = *(const short8*)(Wt + i);
    __syncthreads();

    const int w = t >> 6, lane = t & 63;
    const int m = lane & 15, q = lane >> 4;
    const int r0 = blockIdx.x * 128 + w * 16;
    const int ra = min(r0 + m, N_NODES - 1);

    f32x4 acc[8];
#pragma unroll
    for (int c = 0; c < 8; ++c) acc[c] = (f32x4)(0.f);

#pragma unroll
    for (int kk = 0; kk < 4; ++kk) {
        const int koff = kk * 32 + q * 8;
        short8 a = pack8t(X + (size_t)ra * 128 + koff);
#pragma unroll
        for (int c = 0; c < 8; ++c) {
            short8 bh = *(const short8*)(Ws + (c * 16 + m) * 128 + koff);
            acc[c] = __builtin_amdgcn_mfma_f32_16x16x32_bf16(a, bh, acc[c], 0, 0, 0);
        }
    }

    // C/D layout: col=lane&15, row=q*4+reg  [verified m89/m91]
    const int rb0 = r0 + q * 4;
    f32x4 dv = *(const f32x4*)(dinv + rb0);
#pragma unroll
    for (int c = 0; c < 8; ++c) {
        // feature col = c*16+m -> chunk c>>1, within-chunk (c&1)*16+m
        const size_t coff = ((size_t)(c >> 1) * MROWS) * 32 + (c & 1) * 16 + m;
#pragma unroll
        for (int r = 0; r < 4; ++r) {
            int row = rb0 + r;
            if (row < N_NODES) Yf[coff + (size_t)row * 32] = f2q(acc[c][r] * dv[r]);
        }
    }
}

// ---------- layer-2 GEMM: Y2 = fp8((H @ W2) * dinv); W in LDS, 16 rows/wave ----------
__global__ __launch_bounds__(512) void gemm2_mfma(const short* __restrict__ H,
                                                  const short* __restrict__ Wt,
                                                  const float* __restrict__ dinv,
                                                  unsigned char* __restrict__ Yf) {
    __shared__ short Ws[64 * 128];    // 16 KB
    const int t = threadIdx.x;
    for (int i = t * 8; i < 64 * 128; i += 512 * 8)
        *(short8*)(Ws + i) = *(const short8*)(Wt + i);
    __syncthreads();

    const int w = t >> 6, lane = t & 63;
    const int m = lane & 15, q = lane >> 4;
    const int r0 = blockIdx.x * 128 + w * 16;

    f32x4 acc[4];
#pragma unroll
    for (int c = 0; c < 4; ++c) acc[c] = (f32x4)(0.f);

#pragma unroll
    for (int kk = 0; kk < 4; ++kk) {
        const int koff = kk * 32 + q * 8;
        short8 a = *(const short8*)(H + (size_t)(r0 + m) * 128 + koff);
#pragma unroll
        for (int c = 0; c < 4; ++c) {
            short8 bh = *(const short8*)(Ws + (c * 16 + m) * 128 + koff);
            acc[c] = __builtin_amdgcn_mfma_f32_16x16x32_bf16(a, bh, acc[c], 0, 0, 0);
        }
    }

    const int rb0 = r0 + q * 4;
    f32x4 dv = *(const f32x4*)(dinv + rb0);
#pragma unroll
    for (int c = 0; c < 4; ++c) {
        const int col = c * 16 + m;
#pragma unroll
        for (int r = 0; r < 4; ++r) {
            int row = rb0 + r;
            if (row < N_NODES) Yf[(size_t)row * 64 + col] = f2q(acc[c][r] * dv[r]);
        }
    }
}

// ---------- CSR aggregation, K=128 fp8: XCD-affine feature chunks ----------
// Grid = (bucket, chunk): bid = q*8+x, chunk = x>>1, bucket = q*2+(x&1).
// bid&7 -> XCD (round-robin): each XCD gathers from ONE 3.2MB chunk of Yc
// [4][MROWS][32] -> chunk is L2-resident per XCD, killing the 8x compulsory
// re-fetch. 2 lanes/node, 32 nodes/wave, 8 waves = 256 nodes (full bucket).
// Features independent through ReLU -> chunks write disjoint 64B of h1b row.
__global__ __launch_bounds__(512) void agg_relu(const int2* __restrict__ rinfo,
                                                const int* __restrict__ srcs,
                                                const unsigned char* __restrict__ Yc,
                                                const float* __restrict__ dinv,
                                                const float* __restrict__ b,
                                                short* __restrict__ Hb) {
    int t = threadIdx.x;
    int lane = t & 63, w = t >> 6;
    int x = blockIdx.x & 7;
    int q = blockIdx.x >> 3;
    int c = x >> 1;                            // feature chunk 0..3
    int bucket = q * 2 + (x & 1);
    if (bucket >= NB) return;
    int g = lane >> 1, fl = lane & 1;          // 32 nodes/wave, 2 lanes/node
    int node = (bucket << 8) + w * 32 + g;
    int nd = min(node, N_NODES - 1);
    const unsigned char* Yb = Yc + (size_t)c * MROWS * 32;
    const unsigned fo = (unsigned)(fl << 4);   // 16B per lane within 32B chunk-row
    int2 r = rinfo[nd];
    int e = r.x, len = r.y - r.x;              // exact, >= 1 (self)
    int mx = len;                               // wave-max chain length
    mx = max(mx, __shfl_xor(mx, 2));
    mx = max(mx, __shfl_xor(mx, 4));
    mx = max(mx, __shfl_xor(mx, 8));
    mx = max(mx, __shfl_xor(mx, 16));
    mx = max(mx, __shfl_xor(mx, 32));
    f32x2 a[8];
#pragma unroll
    for (int i = 0; i < 8; ++i) a[i] = (f32x2)(0.f);

    uint4 GA0, GA1;
    unsigned sB0 = 0, sB1 = 0;
    {   // prologue: rows 0,1 in flight; srcs for rows 2,3
        unsigned s0 = (unsigned)srcs[e];                       // len>=1 always
        GA0 = *(const uint4*)(Yb + ((size_t)s0 << 5) + fo);
        if (1 < len) {
            unsigned s1 = (unsigned)srcs[e + 1];
            GA1 = *(const uint4*)(Yb + ((size_t)s1 << 5) + fo);
        }
        if (2 < len) sB0 = (unsigned)srcs[e + 2];
        if (3 < len) sB1 = (unsigned)srcs[e + 3];
    }
    for (int i = 0; i < mx; i += 2) {
        uint4 GB0, GB1;
        if (i + 2 < len) GB0 = *(const uint4*)(Yb + ((size_t)sB0 << 5) + fo);
        if (i + 3 < len) GB1 = *(const uint4*)(Yb + ((size_t)sB1 << 5) + fo);
        unsigned sC0 = sB0, sC1 = sB1;
        if (i + 4 < len) sC0 = (unsigned)srcs[e + i + 4];
        if (i + 5 < len) sC1 = (unsigned)srcs[e + i + 5];
        if (i < len)     acc16(a, GA0);
        if (i + 1 < len) acc16(a, GA1);
        GA0 = GB0; GA1 = GB1; sB0 = sC0; sB1 = sC1;
    }

    // epilogue: lane holds features c*32 + fl*16 + [0..16) of its node
    float sc = dinv[nd];
    const float4* bf = (const float4*)(b + c * 32 + fl * 16);
    float bb[16];
    *(float4*)(bb + 0)  = bf[0];
    *(float4*)(bb + 4)  = bf[1];
    *(float4*)(bb + 8)  = bf[2];
    *(float4*)(bb + 12) = bf[3];
    unsigned u[8];
#pragma unroll
    for (int k = 0; k < 8; ++k) {
        float v0 = fmaxf(sc * a[k][0] + bb[2 * k], 0.f);
        float v1 = fmaxf(sc * a[k][1] + bb[2 * k + 1], 0.f);
        u[k] = pk2(v0, v1);
    }
    if (node < N_NODES) {
        uint4* hp = (uint4*)((char*)Hb + ((size_t)node << 8) + (c << 6) + (fl << 5));
        hp[0] = make_uint4(u[0], u[1], u[2], u[3]);
        hp[1] = make_uint4(u[4], u[5], u[6], u[7]);
    }
}

// ---------- CSR aggregation, K=64 fp8: group-per-node predicated + log_softmax ----------
__global__ __launch_bounds__(256) void agg_lsm(const int2* __restrict__ rinfo,
                                               const int* __restrict__ srcs,
                                               const unsigned char* __restrict__ Yf,
                                               const float* __restrict__ dinv,
                                               const float* __restrict__ b,
                                               float* __restrict__ out) {
    int t = threadIdx.x;
    int lane = t & 63, w = t >> 6;
    int g = lane >> 2, fl = lane & 3;          // 16 groups of 4 lanes
    int node = blockIdx.x * 64 + w * 16 + g;   // last block partially OOB
    int nd = min(node, N_NODES - 1);
    const unsigned fo = (unsigned)(fl << 4);   // 16B per lane within 64B row
    int2 r = rinfo[nd];
    int e = r.x, len = r.y - r.x;
    int mx = len;
    mx = max(mx, __shfl_xor(mx, 4));
    mx = max(mx, __shfl_xor(mx, 8));
    mx = max(mx, __shfl_xor(mx, 16));
    mx = max(mx, __shfl_xor(mx, 32));
    f32x2 a[8];
#pragma unroll
    for (int i = 0; i < 8; ++i) a[i] = (f32x2)(0.f);

    uint4 GA0, GA1;
    unsigned sB0 = 0, sB1 = 0;
    {
        unsigned s0 = (unsigned)srcs[e];
        GA0 = *(const uint4*)(Yf + ((s0 << 6) + fo));
        if (1 < len) {
            unsigned s1 = (unsigned)srcs[e + 1];
            GA1 = *(const uint4*)(Yf + ((s1 << 6) + fo));
        }
        if (2 < len) sB0 = (unsigned)srcs[e + 2];
        if (3 < len) sB1 = (unsigned)srcs[e + 3];
    }
    for (int i = 0; i < mx; i += 2) {
        uint4 GB0, GB1;
        if (i + 2 < len) GB0 = *(const uint4*)(Yf + ((sB0 << 6) + fo));
        if (i + 3 < len) GB1 = *(const uint4*)(Yf + ((sB1 << 6) + fo));
        unsigned sC0 = sB0, sC1 = sB1;
        if (i + 4 < len) sC0 = (unsigned)srcs[e + i + 4];
        if (i + 5 < len) sC1 = (unsigned)srcs[e + i + 5];
        if (i < len)     acc16(a, GA0);
        if (i + 1 < len) acc16(a, GA1);
        GA0 = GB0; GA1 = GB1; sB0 = sC0; sB1 = sC1;
    }

    // epilogue: lane holds final features [16*fl, 16*fl+16) of its node
    float sc = dinv[nd];
    const float4* bf = (const float4*)b;
    float bb[16];
    *(float4*)(bb + 0)  = bf[fl * 4 + 0];
    *(float4*)(bb + 4)  = bf[fl * 4 + 1];
    *(float4*)(bb + 8)  = bf[fl * 4 + 2];
    *(float4*)(bb + 12) = bf[fl * 4 + 3];
    float v[16];
#pragma unroll
    for (int j = 0; j < 16; ++j) v[j] = sc * a[j >> 1][j & 1] + bb[j];
    float m = v[0];
#pragma unroll
    for (int j = 1; j < 16; ++j) m = fmaxf(m, v[j]);
    m = fmaxf(m, __shfl_xor(m, 1));            // fl = lane bits 0..1
    m = fmaxf(m, __shfl_xor(m, 2));
    float su = 0.f;
#pragma unroll
    for (int j = 0; j < 16; ++j) su += __expf(v[j] - m);
    su += __shfl_xor(su, 1);
    su += __shfl_xor(su, 2);
    float ls = m + logf(su);
    if (node < N_NODES) {
        float4* op = (float4*)out + (size_t)node * 16 + fl * 4;
        op[0] = make_float4(v[0] - ls,  v[1] - ls,  v[2] - ls,  v[3] - ls);
        op[1] = make_float4(v[4] - ls,  v[5] - ls,  v[6] - ls,  v[7] - ls);
        op[2] = make_float4(v[8] - ls,  v[9] - ls,  v[10] - ls, v[11] - ls);
        op[3] = make_float4(v[12] - ls, v[13] - ls, v[14] - ls, v[15] - ls);
    }
}

extern "C" void kernel_launch(void* const* d_in, const int* in_sizes, int n_in,
                              void* d_out, int out_size, void* d_ws, size_t ws_size,
                              hipStream_t stream) {
    const float* x  = (const float*)d_in[0];
    const float* W1 = (const float*)d_in[1];
    const float* b1 = (const float*)d_in[2];
    const float* W2 = (const float*)d_in[3];
    const float* b2 = (const float*)d_in[4];
    const int* edge = (const int*)d_in[5];
    const int* src = edge;
    const int* dst = edge + N_EDGES;
    float* out = (float*)d_out;

    char* ws = (char*)d_ws;
    int*           bcnt  = (int*)(ws + 0);             //     1,564
    int*           boffs = (int*)(ws + 2048);          //     1,568
    int*           bcur  = (int*)(ws + 4096);          //     1,564
    float*         dinv  = (float*)(ws + 6144);        //   400,384 (MROWS)
    int2*          rinfo = (int2*)(ws + 406528);       //   800,000
    int*           srcs  = (int*)(ws + 1206528);       //  6,800,000 (exact CSR, self folded)
    unsigned*      pairs = (unsigned*)(ws + 14012672); //  6,400,000
    short*         w1h   = (short*)(ws + 20412672);    //     32,768
    short*         w2h   = (short*)(ws + 20445440);    //     16,384
    unsigned char* y1f   = (unsigned char*)(ws + 20461824); // 12,812,288 ([4][MROWS][32] fp8)
    short*         h1b   = (short*)(ws + 33274112);    // 25,624,576 (MROWS*128 bf16)
    unsigned char* y2f   = (unsigned char*)(ws + 58898688); //  6,406,144 (MROWS*64 fp8)
    // ends ~65.3 MB

    // ---- init: bcnt zeros ----
    init_misc<<<1, 512, 0, stream>>>(bcnt);

    // ---- CSR build: bucket histogram -> scan -> scatter -> exact bucket fill ----
    bucket_count<<<512, 256, 0, stream>>>(dst, bcnt);
    bucket_scan<<<1, 512, 0, stream>>>(bcnt, boffs, bcur);
    bucket_scatter<<<(N_EDGES + CH - 1) / CH, 256, 0, stream>>>(src, dst, bcur, pairs);
    csr_fill_bucket<<<NB, 256, 0, stream>>>(pairs, boffs, rinfo, dinv, srcs);

    // ---- weight conversion ----
    convert_w<<<(128 * 128 + 64 * 128 + 255) / 256, 256, 0, stream>>>(W1, W2, w1h, w2h);

    // ---- layer 1 ----
    gemm1_mfma<<<MROWS / 128, 512, 0, stream>>>(x, w1h, dinv, y1f);
    // (bucket, chunk) grid: q*8+x, x -> XCD (round-robin), chunk = x>>1
    agg_relu<<<196 * 8, 512, 0, stream>>>(rinfo, srcs, y1f, dinv, b1, h1b);

    // ---- layer 2 ----
    gemm2_mfma<<<MROWS / 128, 512, 0, stream>>>(h1b, w2h, dinv, y2f);
    agg_lsm<<<(N_NODES + 63) / 64, 256, 0, stream>>>(rinfo, srcs, y2f, dinv, b2, out);
}

// Round 7
// 257.747 us; speedup vs baseline: 1.1304x; 1.1304x over previous
//
#include <hip/hip_runtime.h>
#include <math.h>

#define N_NODES 100000
#define N_EDGES 1600000
#define NB 391              // dst buckets (d>>8), 256 nodes each
#define MROWS 100096        // 782*128, padded row count for guard-free tiles
#define CH 3200             // edges per bucket_scatter block -> 500 blocks

typedef __attribute__((ext_vector_type(8))) short short8;  // 8 bf16 = 4 VGPRs
typedef __attribute__((ext_vector_type(4))) float f32x4;
typedef __attribute__((ext_vector_type(2))) float f32x2;

__device__ __forceinline__ short f2b(float f) {            // fp32 -> bf16 RNE
    unsigned u = __float_as_uint(f);
    unsigned r = (u + 0x7FFFu + ((u >> 16) & 1u)) >> 16;
    return (short)r;
}
__device__ __forceinline__ unsigned pk2(float a, float b) {
    return (unsigned)(unsigned short)f2b(a) | ((unsigned)(unsigned short)f2b(b) << 16);
}
// f32 -> fp8 e4m3 (OCP), single byte
__device__ __forceinline__ unsigned char f2q(float v) {
    return (unsigned char)(__builtin_amdgcn_cvt_pk_fp8_f32(v, 0.f, 0, false) & 0xFF);
}
// accumulate 4 fp8 (one uint) into a[0..1] as packed f32x2 (v_pk_add_f32)
__device__ __forceinline__ void acc2(f32x2* a, unsigned u) {
    a[0] += __builtin_amdgcn_cvt_pk_f32_fp8((int)u, false);
    a[1] += __builtin_amdgcn_cvt_pk_f32_fp8((int)u, true);
}
// accumulate 16 fp8 (one uint4) into a[0..7]
__device__ __forceinline__ void acc16(f32x2* a, uint4 u) {
    acc2(a + 0, u.x); acc2(a + 2, u.y); acc2(a + 4, u.z); acc2(a + 6, u.w);
}

// pack 8 fp32 -> 8 bf16 (truncate; 1 v_perm per 2 elems)
__device__ __forceinline__ short8 pack8t(const float* __restrict__ p) {
    float4 v0 = ((const float4*)p)[0];
    float4 v1 = ((const float4*)p)[1];
    union { unsigned u[4]; short8 s; } r;
    r.u[0] = __builtin_amdgcn_perm(__float_as_uint(v0.y), __float_as_uint(v0.x), 0x07060302u);
    r.u[1] = __builtin_amdgcn_perm(__float_as_uint(v0.w), __float_as_uint(v0.z), 0x07060302u);
    r.u[2] = __builtin_amdgcn_perm(__float_as_uint(v1.y), __float_as_uint(v1.x), 0x07060302u);
    r.u[3] = __builtin_amdgcn_perm(__float_as_uint(v1.w), __float_as_uint(v1.z), 0x07060302u);
    return r.s;
}

// ---------- init: bcnt zeros ----------
__global__ __launch_bounds__(512) void init_misc(int* __restrict__ bcnt) {
    int t = threadIdx.x;
    if (t < NB) bcnt[t] = 0;
}

// ---------- bucket histogram (LDS-staged) ----------
__global__ __launch_bounds__(256) void bucket_count(const int* __restrict__ dst,
                                                    int* __restrict__ bcnt) {
    __shared__ int h[NB];
    int t = threadIdx.x;
    for (int i = t; i < NB; i += 256) h[i] = 0;
    __syncthreads();
    for (int e = blockIdx.x * 256 + t; e < N_EDGES; e += gridDim.x * 256)
        atomicAdd(&h[dst[e] >> 8], 1);
    __syncthreads();
    for (int i = t; i < NB; i += 256)
        if (h[i]) atomicAdd(&bcnt[i], h[i]);
}

// ---------- bucket-level exclusive scan (one block) ----------
__global__ __launch_bounds__(512) void bucket_scan(const int* __restrict__ bcnt,
                                                   int* __restrict__ boffs,
                                                   int* __restrict__ bcur) {
    __shared__ int s[512];
    int t = threadIdx.x;
    int v = (t < NB) ? bcnt[t] : 0;
    s[t] = v;
    __syncthreads();
    for (int off = 1; off < 512; off <<= 1) {
        int u = (t >= off) ? s[t - off] : 0;
        __syncthreads();
        s[t] += u;
        __syncthreads();
    }
    if (t < NB) {
        int ex = s[t] - v;
        boffs[t] = ex;
        bcur[t] = ex;
    }
    if (t == 0) boffs[NB] = N_EDGES;
}

// ---------- scatter edges into bucket-grouped packed list ----------
// LDS counting-sort per block, then CONTIGUOUS run writes: 391 sorted runs of
// ~8 words instead of 3200 random 4B writes (kills partial-line write storm).
// packed word: (d&255)<<24 | src   (src < 2^24)
__global__ __launch_bounds__(512) void bucket_scatter(const int* __restrict__ src,
                                                      const int* __restrict__ dst,
                                                      int* __restrict__ bcur,
                                                      unsigned* __restrict__ pairs) {
    __shared__ unsigned lw[CH];
    __shared__ unsigned lw2[CH];
    __shared__ int gdst[CH];
    __shared__ short lb[CH];
    __shared__ int s[512];
    __shared__ int cnt[NB];
    __shared__ int lstart[NB];
    int t = threadIdx.x;
    int e0 = blockIdx.x * CH;
    int n = min(CH, N_EDGES - e0);
    for (int i = t; i < NB; i += 512) cnt[i] = 0;
    __syncthreads();
    for (int i = t; i < n; i += 512) {
        int sv = src[e0 + i], d = dst[e0 + i];
        lw[i] = ((unsigned)(d & 255) << 24) | (unsigned)sv;
        int b = d >> 8;
        lb[i] = (short)b;
        atomicAdd(&cnt[b], 1);
    }
    __syncthreads();
    int v = (t < NB) ? cnt[t] : 0;
    s[t] = v;
    __syncthreads();
    for (int off = 1; off < 512; off <<= 1) {
        int u = (t >= off) ? s[t - off] : 0;
        __syncthreads();
        s[t] += u;
        __syncthreads();
    }
    if (t < NB) {
        s[t] -= v;                               // local exclusive offset
        lstart[t] = v ? atomicAdd(&bcur[t], v) : 0;
        cnt[t] = 0;                              // reuse as local cursor
    }
    __syncthreads();
    for (int i = t; i < n; i += 512) {
        int b = lb[i];
        int r = atomicAdd(&cnt[b], 1);
        int sl = s[b] + r;
        lw2[sl] = lw[i];
        gdst[sl] = lstart[b] + r;
    }
    __syncthreads();
    for (int j = t; j < n; j += 512)             // consecutive j -> consecutive dest
        pairs[gdst[j]] = lw2[j];
}

// ---------- bucket-local CSR fill; self-loop at slot 0; NO padding ----------
__global__ __launch_bounds__(256) void csr_fill_bucket(const unsigned* __restrict__ pairs,
                                                       const int* __restrict__ boffs,
                                                       int2* __restrict__ rinfo,
                                                       float* __restrict__ dinv,
                                                       int* __restrict__ srcs) {
    __shared__ int lcnt[256];
    __shared__ int ls[256];
    int t = threadIdx.x, b = blockIdx.x, base = b << 8;
    lcnt[t] = 0;
    __syncthreads();
    int lo_e = boffs[b], hi_e = boffs[b + 1];
    for (int i = lo_e + t; i < hi_e; i += 256)
        atomicAdd(&lcnt[pairs[i] >> 24], 1);
    __syncthreads();
    int c = lcnt[t];
    int len = c + 1;                   // self-loop included, exact length
    ls[t] = len;
    __syncthreads();
    for (int off = 1; off < 256; off <<= 1) {
        int u = (t >= off) ? ls[t - off] : 0;
        __syncthreads();
        ls[t] += u;
        __syncthreads();
    }
    int rp = lo_e + base + ls[t] - len;   // edges-before + selves-before
    int node = base + t;
    if (node < N_NODES) {
        rinfo[node] = make_int2(rp, rp + len);
        dinv[node] = rsqrtf((float)len);
        srcs[rp] = node;               // folded self-loop at slot 0
    }
    __syncthreads();
    lcnt[t] = rp + 1;                  // reuse as global cursor (slot 0 = self)
    __syncthreads();
    for (int i = lo_e + t; i < hi_e; i += 256) {
        unsigned p = pairs[i];
        int li = p >> 24;
        int pos = atomicAdd(&lcnt[li], 1);
        srcs[pos] = (int)(p & 0xFFFFFFu);
    }
}

// ---------- W1 [128][128] + W2 [128][64] fp32 -> Wt [N][128] bf16 ----------
__global__ __launch_bounds__(256) void convert_w(const float* __restrict__ W1,
                                                 const float* __restrict__ W2,
                                                 short* __restrict__ w1h,
                                                 short* __restrict__ w2h) {
    int id = blockIdx.x * 256 + threadIdx.x;
    if (id < 128 * 128) {
        int n = id >> 7, k = id & 127;
        w1h[id] = f2b(W1[k * 128 + n]);
    } else if (id < 128 * 128 + 64 * 128) {
        int j = id - 128 * 128;
        int n = j >> 7, k = j & 127;
        w2h[j] = f2b(W2[k * 64 + n]);
    }
}

// ---------- layer-1 GEMM: Y1 = fp8((X @ W1) * dinv); W in LDS, 16 rows/wave ----------
__global__ __launch_bounds__(512) void gemm1_mfma(const float* __restrict__ X,
                                                  const short* __restrict__ Wt,
                                                  const float* __restrict__ dinv,
                                                  unsigned char* __restrict__ Yf) {
    __shared__ short Ws[128 * 128];   // 32 KB
    const int t = threadIdx.x;
    for (int i = t * 8; i < 128 * 128; i += 512 * 8)
        *(short8*)(Ws + i) = *(const short8*)(Wt + i);
    __syncthreads();

    const int w = t >> 6, lane = t & 63;
    const int m = lane & 15, q = lane >> 4;
    const int r0 = blockIdx.x * 128 + w * 16;
    const int ra = min(r0 + m, N_NODES - 1);

    f32x4 acc[8];
#pragma unroll
    for (int c = 0; c < 8; ++c) acc[c] = (f32x4)(0.f);

#pragma unroll
    for (int kk = 0; kk < 4; ++kk) {
        const int koff = kk * 32 + q * 8;
        short8 a = pack8t(X + (size_t)ra * 128 + koff);
#pragma unroll
        for (int c = 0; c < 8; ++c) {
            short8 bh = *(const short8*)(Ws + (c * 16 + m) * 128 + koff);
            acc[c] = __builtin_amdgcn_mfma_f32_16x16x32_bf16(a, bh, acc[c], 0, 0, 0);
        }
    }

    // C/D layout: col=lane&15, row=q*4+reg  [verified m89/m91]
    const int rb0 = r0 + q * 4;
    f32x4 dv = *(const f32x4*)(dinv + rb0);
#pragma unroll
    for (int c = 0; c < 8; ++c) {
        const int col = c * 16 + m;
#pragma unroll
        for (int r = 0; r < 4; ++r) {
            int row = rb0 + r;
            if (row < N_NODES) Yf[(size_t)row * 128 + col] = f2q(acc[c][r] * dv[r]);
        }
    }
}

// ---------- layer-2 GEMM: Y2 = fp8((H @ W2) * dinv); W in LDS, 16 rows/wave ----------
__global__ __launch_bounds__(512) void gemm2_mfma(const short* __restrict__ H,
                                                  const short* __restrict__ Wt,
                                                  const float* __restrict__ dinv,
                                                  unsigned char* __restrict__ Yf) {
    __shared__ short Ws[64 * 128];    // 16 KB
    const int t = threadIdx.x;
    for (int i = t * 8; i < 64 * 128; i += 512 * 8)
        *(short8*)(Ws + i) = *(const short8*)(Wt + i);
    __syncthreads();

    const int w = t >> 6, lane = t & 63;
    const int m = lane & 15, q = lane >> 4;
    const int r0 = blockIdx.x * 128 + w * 16;

    f32x4 acc[4];
#pragma unroll
    for (int c = 0; c < 4; ++c) acc[c] = (f32x4)(0.f);

#pragma unroll
    for (int kk = 0; kk < 4; ++kk) {
        const int koff = kk * 32 + q * 8;
        short8 a = *(const short8*)(H + (size_t)(r0 + m) * 128 + koff);
#pragma unroll
        for (int c = 0; c < 4; ++c) {
            short8 bh = *(const short8*)(Ws + (c * 16 + m) * 128 + koff);
            acc[c] = __builtin_amdgcn_mfma_f32_16x16x32_bf16(a, bh, acc[c], 0, 0, 0);
        }
    }

    const int rb0 = r0 + q * 4;
    f32x4 dv = *(const f32x4*)(dinv + rb0);
#pragma unroll
    for (int c = 0; c < 4; ++c) {
        const int col = c * 16 + m;
#pragma unroll
        for (int r = 0; r < 4; ++r) {
            int row = rb0 + r;
            if (row < N_NODES) Yf[(size_t)row * 64 + col] = f2q(acc[c][r] * dv[r]);
        }
    }
}

// ---------- CSR aggregation, K=128 fp8: depth-6 pipeline, natural order ----------
// 8-lane group owns one node. Three 2-row slots in fixed registers: a slot's
// accumulate happens one full iteration after its gather was issued (6 rows +
// 6 srcs in flight per group). All ops predicated on row<len. Natural node
// order keeps block totals balanced (Poisson(17)/32-node CV ~ 4%).
__global__ __launch_bounds__(256) void agg_relu(const int2* __restrict__ rinfo,
                                                const int* __restrict__ srcs,
                                                const unsigned char* __restrict__ Yf,
                                                const float* __restrict__ dinv,
                                                const float* __restrict__ b,
                                                short* __restrict__ Hb) {
    int t = threadIdx.x;
    int lane = t & 63, w = t >> 6;
    int g = lane >> 3, fl = lane & 7;          // 8 groups of 8 lanes
    int node = blockIdx.x * 32 + w * 8 + g;    // N_NODES % 32 == 0
    const unsigned fo = (unsigned)(fl << 4);   // 16B per lane within 128B row
    int2 r = rinfo[node];
    int e = r.x, len = r.y - r.x;              // exact, >= 1 (self)
    int mx = len;                               // wave-max chain length
    mx = max(mx, __shfl_xor(mx, 8));
    mx = max(mx, __shfl_xor(mx, 16));
    mx = max(mx, __shfl_xor(mx, 32));
    f32x2 a[8];
#pragma unroll
    for (int i = 0; i < 8; ++i) a[i] = (f32x2)(0.f);

    auto ld = [&](int i) -> unsigned {
        unsigned v = 0;
        if (i < len) v = (unsigned)srcs[e + i];
        return v;
    };
    auto gth = [&](unsigned s) -> uint4 {
        return *(const uint4*)(Yf + ((s << 7) + fo));
    };

    unsigned sA0 = ld(0), sA1 = ld(1), sB0 = ld(2), sB1 = ld(3), sC0 = ld(4), sC1 = ld(5);
    uint4 GA0, GA1, GB0, GB1, GC0, GC1;
    if (0 < len) GA0 = gth(sA0);
    if (1 < len) GA1 = gth(sA1);
    if (2 < len) GB0 = gth(sB0);
    if (3 < len) GB1 = gth(sB1);
    if (4 < len) GC0 = gth(sC0);
    if (5 < len) GC1 = gth(sC1);
    sA0 = ld(6); sA1 = ld(7); sB0 = ld(8); sB1 = ld(9); sC0 = ld(10); sC1 = ld(11);

    for (int i = 0; i < mx; i += 6) {
        if (i < len)      acc16(a, GA0);
        if (i + 1 < len)  acc16(a, GA1);
        if (i + 6 < len)  GA0 = gth(sA0);
        if (i + 7 < len)  GA1 = gth(sA1);
        if (i + 2 < len)  acc16(a, GB0);
        if (i + 3 < len)  acc16(a, GB1);
        if (i + 8 < len)  GB0 = gth(sB0);
        if (i + 9 < len)  GB1 = gth(sB1);
        if (i + 4 < len)  acc16(a, GC0);
        if (i + 5 < len)  acc16(a, GC1);
        if (i + 10 < len) GC0 = gth(sC0);
        if (i + 11 < len) GC1 = gth(sC1);
        sA0 = ld(i + 12); sA1 = ld(i + 13);
        sB0 = ld(i + 14); sB1 = ld(i + 15);
        sC0 = ld(i + 16); sC1 = ld(i + 17);
    }

    // epilogue: lane holds final features [16*fl, 16*fl+16) of its node
    float sc = dinv[node];
    const float4* bf = (const float4*)b;
    float bb[16];
    *(float4*)(bb + 0)  = bf[fl * 4 + 0];
    *(float4*)(bb + 4)  = bf[fl * 4 + 1];
    *(float4*)(bb + 8)  = bf[fl * 4 + 2];
    *(float4*)(bb + 12) = bf[fl * 4 + 3];
    unsigned u[8];
#pragma unroll
    for (int k = 0; k < 8; ++k) {
        float v0 = fmaxf(sc * a[k][0] + bb[2 * k], 0.f);
        float v1 = fmaxf(sc * a[k][1] + bb[2 * k + 1], 0.f);
        u[k] = pk2(v0, v1);
    }
    uint4* hp = (uint4*)Hb + (size_t)node * 16 + fl * 2;
    hp[0] = make_uint4(u[0], u[1], u[2], u[3]);
    hp[1] = make_uint4(u[4], u[5], u[6], u[7]);
}

// ---------- CSR aggregation, K=64 fp8: depth-2 predicated + log_softmax (CONTROL) ----------
__global__ __launch_bounds__(256) void agg_lsm(const int2* __restrict__ rinfo,
                                               const int* __restrict__ srcs,
                                               const unsigned char* __restrict__ Yf,
                                               const float* __restrict__ dinv,
                                               const float* __restrict__ b,
                                               float* __restrict__ out) {
    int t = threadIdx.x;
    int lane = t & 63, w = t >> 6;
    int g = lane >> 2, fl = lane & 3;          // 16 groups of 4 lanes
    int node = blockIdx.x * 64 + w * 16 + g;   // last block partially OOB
    int nd = min(node, N_NODES - 1);
    const unsigned fo = (unsigned)(fl << 4);   // 16B per lane within 64B row
    int2 r = rinfo[nd];
    int e = r.x, len = r.y - r.x;
    int mx = len;
    mx = max(mx, __shfl_xor(mx, 4));
    mx = max(mx, __shfl_xor(mx, 8));
    mx = max(mx, __shfl_xor(mx, 16));
    mx = max(mx, __shfl_xor(mx, 32));
    f32x2 a[8];
#pragma unroll
    for (int i = 0; i < 8; ++i) a[i] = (f32x2)(0.f);

    uint4 GA0, GA1;
    unsigned sB0 = 0, sB1 = 0;
    {
        unsigned s0 = (unsigned)srcs[e];
        GA0 = *(const uint4*)(Yf + ((s0 << 6) + fo));
        if (1 < len) {
            unsigned s1 = (unsigned)srcs[e + 1];
            GA1 = *(const uint4*)(Yf + ((s1 << 6) + fo));
        }
        if (2 < len) sB0 = (unsigned)srcs[e + 2];
        if (3 < len) sB1 = (unsigned)srcs[e + 3];
    }
    for (int i = 0; i < mx; i += 2) {
        uint4 GB0, GB1;
        if (i + 2 < len) GB0 = *(const uint4*)(Yf + ((sB0 << 6) + fo));
        if (i + 3 < len) GB1 = *(const uint4*)(Yf + ((sB1 << 6) + fo));
        unsigned sC0 = sB0, sC1 = sB1;
        if (i + 4 < len) sC0 = (unsigned)srcs[e + i + 4];
        if (i + 5 < len) sC1 = (unsigned)srcs[e + i + 5];
        if (i < len)     acc16(a, GA0);
        if (i + 1 < len) acc16(a, GA1);
        GA0 = GB0; GA1 = GB1; sB0 = sC0; sB1 = sC1;
    }

    // epilogue: lane holds final features [16*fl, 16*fl+16) of its node
    float sc = dinv[nd];
    const float4* bf = (const float4*)b;
    float bb[16];
    *(float4*)(bb + 0)  = bf[fl * 4 + 0];
    *(float4*)(bb + 4)  = bf[fl * 4 + 1];
    *(float4*)(bb + 8)  = bf[fl * 4 + 2];
    *(float4*)(bb + 12) = bf[fl * 4 + 3];
    float v[16];
#pragma unroll
    for (int j = 0; j < 16; ++j) v[j] = sc * a[j >> 1][j & 1] + bb[j];
    float m = v[0];
#pragma unroll
    for (int j = 1; j < 16; ++j) m = fmaxf(m, v[j]);
    m = fmaxf(m, __shfl_xor(m, 1));            // fl = lane bits 0..1
    m = fmaxf(m, __shfl_xor(m, 2));
    float su = 0.f;
#pragma unroll
    for (int j = 0; j < 16; ++j) su += __expf(v[j] - m);
    su += __shfl_xor(su, 1);
    su += __shfl_xor(su, 2);
    float ls = m + logf(su);
    if (node < N_NODES) {
        float4* op = (float4*)out + (size_t)node * 16 + fl * 4;
        op[0] = make_float4(v[0] - ls,  v[1] - ls,  v[2] - ls,  v[3] - ls);
        op[1] = make_float4(v[4] - ls,  v[5] - ls,  v[6] - ls,  v[7] - ls);
        op[2] = make_float4(v[8] - ls,  v[9] - ls,  v[10] - ls, v[11] - ls);
        op[3] = make_float4(v[12] - ls, v[13] - ls, v[14] - ls, v[15] - ls);
    }
}

extern "C" void kernel_launch(void* const* d_in, const int* in_sizes, int n_in,
                              void* d_out, int out_size, void* d_ws, size_t ws_size,
                              hipStream_t stream) {
    const float* x  = (const float*)d_in[0];
    const float* W1 = (const float*)d_in[1];
    const float* b1 = (const float*)d_in[2];
    const float* W2 = (const float*)d_in[3];
    const float* b2 = (const float*)d_in[4];
    const int* edge = (const int*)d_in[5];
    const int* src = edge;
    const int* dst = edge + N_EDGES;
    float* out = (float*)d_out;

    char* ws = (char*)d_ws;
    int*           bcnt  = (int*)(ws + 0);             //     1,564
    int*           boffs = (int*)(ws + 2048);          //     1,568
    int*           bcur  = (int*)(ws + 4096);          //     1,564
    float*         dinv  = (float*)(ws + 6144);        //   400,384 (MROWS)
    int2*          rinfo = (int2*)(ws + 406528);       //   800,000
    int*           srcs  = (int*)(ws + 1206528);       //  6,800,000 (exact CSR, self folded)
    unsigned*      pairs = (unsigned*)(ws + 14012672); //  6,400,000
    short*         w1h   = (short*)(ws + 20412672);    //     32,768
    short*         w2h   = (short*)(ws + 20445440);    //     16,384
    unsigned char* y1f   = (unsigned char*)(ws + 20461824); // 12,812,288 (MROWS*128 fp8)
    short*         h1b   = (short*)(ws + 33274112);    // 25,624,576 (MROWS*128 bf16)
    unsigned char* y2f   = (unsigned char*)(ws + 58898688); //  6,406,144 (MROWS*64 fp8)
    // ends ~65.3 MB

    // ---- init: bcnt zeros ----
    init_misc<<<1, 512, 0, stream>>>(bcnt);

    // ---- CSR build: bucket histogram -> scan -> sorted scatter -> exact bucket fill ----
    bucket_count<<<512, 256, 0, stream>>>(dst, bcnt);
    bucket_scan<<<1, 512, 0, stream>>>(bcnt, boffs, bcur);
    bucket_scatter<<<(N_EDGES + CH - 1) / CH, 512, 0, stream>>>(src, dst, bcur, pairs);
    csr_fill_bucket<<<NB, 256, 0, stream>>>(pairs, boffs, rinfo, dinv, srcs);

    // ---- weight conversion ----
    convert_w<<<(128 * 128 + 64 * 128 + 255) / 256, 256, 0, stream>>>(W1, W2, w1h, w2h);

    // ---- layer 1 ----
    gemm1_mfma<<<MROWS / 128, 512, 0, stream>>>(x, w1h, dinv, y1f);
    agg_relu<<<N_NODES / 32, 256, 0, stream>>>(rinfo, srcs, y1f, dinv, b1, h1b);

    // ---- layer 2 ----
    gemm2_mfma<<<MROWS / 128, 512, 0, stream>>>(h1b, w2h, dinv, y2f);
    agg_lsm<<<(N_NODES + 63) / 64, 256, 0, stream>>>(rinfo, srcs, y2f, dinv, b2, out);
}

// Round 8
// 253.760 us; speedup vs baseline: 1.1481x; 1.0157x over previous
//
#include <hip/hip_runtime.h>
#include <math.h>

#define N_NODES 100000
#define N_EDGES 1600000
#define NB 391              // dst buckets (d>>8), 256 nodes each
#define MROWS 100096        // 782*128, padded row count for guard-free tiles
#define CH 3200             // edges per bucket_scatter block -> 500 blocks

typedef __attribute__((ext_vector_type(8))) short short8;  // 8 bf16 = 4 VGPRs
typedef __attribute__((ext_vector_type(4))) float f32x4;
typedef __attribute__((ext_vector_type(2))) float f32x2;

__device__ __forceinline__ short f2b(float f) {            // fp32 -> bf16 RNE
    unsigned u = __float_as_uint(f);
    unsigned r = (u + 0x7FFFu + ((u >> 16) & 1u)) >> 16;
    return (short)r;
}
__device__ __forceinline__ unsigned pk2(float a, float b) {
    return (unsigned)(unsigned short)f2b(a) | ((unsigned)(unsigned short)f2b(b) << 16);
}
// f32 -> fp8 e4m3 (OCP), single byte
__device__ __forceinline__ unsigned char f2q(float v) {
    return (unsigned char)(__builtin_amdgcn_cvt_pk_fp8_f32(v, 0.f, 0, false) & 0xFF);
}
// accumulate 4 fp8 (one uint) into a[0..1] as packed f32x2 (v_pk_add_f32)
__device__ __forceinline__ void acc2(f32x2* a, unsigned u) {
    a[0] += __builtin_amdgcn_cvt_pk_f32_fp8((int)u, false);
    a[1] += __builtin_amdgcn_cvt_pk_f32_fp8((int)u, true);
}
// accumulate 16 fp8 (one uint4) into a[0..7]
__device__ __forceinline__ void acc16(f32x2* a, uint4 u) {
    acc2(a + 0, u.x); acc2(a + 2, u.y); acc2(a + 4, u.z); acc2(a + 6, u.w);
}

// pack 8 fp32 -> 8 bf16 (truncate; 1 v_perm per 2 elems)
__device__ __forceinline__ short8 pack8t(const float* __restrict__ p) {
    float4 v0 = ((const float4*)p)[0];
    float4 v1 = ((const float4*)p)[1];
    union { unsigned u[4]; short8 s; } r;
    r.u[0] = __builtin_amdgcn_perm(__float_as_uint(v0.y), __float_as_uint(v0.x), 0x07060302u);
    r.u[1] = __builtin_amdgcn_perm(__float_as_uint(v0.w), __float_as_uint(v0.z), 0x07060302u);
    r.u[2] = __builtin_amdgcn_perm(__float_as_uint(v1.y), __float_as_uint(v1.x), 0x07060302u);
    r.u[3] = __builtin_amdgcn_perm(__float_as_uint(v1.w), __float_as_uint(v1.z), 0x07060302u);
    return r.s;
}

// ---------- init: bcnt zeros ----------
__global__ __launch_bounds__(512) void init_misc(int* __restrict__ bcnt) {
    int t = threadIdx.x;
    if (t < NB) bcnt[t] = 0;
}

// ---------- bucket histogram (LDS-staged) ----------
__global__ __launch_bounds__(256) void bucket_count(const int* __restrict__ dst,
                                                    int* __restrict__ bcnt) {
    __shared__ int h[NB];
    int t = threadIdx.x;
    for (int i = t; i < NB; i += 256) h[i] = 0;
    __syncthreads();
    for (int e = blockIdx.x * 256 + t; e < N_EDGES; e += gridDim.x * 256)
        atomicAdd(&h[dst[e] >> 8], 1);
    __syncthreads();
    for (int i = t; i < NB; i += 256)
        if (h[i]) atomicAdd(&bcnt[i], h[i]);
}

// ---------- bucket-level exclusive scan (one block) ----------
__global__ __launch_bounds__(512) void bucket_scan(const int* __restrict__ bcnt,
                                                   int* __restrict__ boffs,
                                                   int* __restrict__ bcur) {
    __shared__ int s[512];
    int t = threadIdx.x;
    int v = (t < NB) ? bcnt[t] : 0;
    s[t] = v;
    __syncthreads();
    for (int off = 1; off < 512; off <<= 1) {
        int u = (t >= off) ? s[t - off] : 0;
        __syncthreads();
        s[t] += u;
        __syncthreads();
    }
    if (t < NB) {
        int ex = s[t] - v;
        boffs[t] = ex;
        bcur[t] = ex;
    }
    if (t == 0) boffs[NB] = N_EDGES;
}

// ---------- scatter edges into bucket-grouped packed list ----------
// LDS counting-sort per block, then CONTIGUOUS run writes: 391 sorted runs of
// ~8 words instead of 3200 random 4B writes (kills partial-line write storm).
// packed word: (d&255)<<24 | src   (src < 2^24)
__global__ __launch_bounds__(512) void bucket_scatter(const int* __restrict__ src,
                                                      const int* __restrict__ dst,
                                                      int* __restrict__ bcur,
                                                      unsigned* __restrict__ pairs) {
    __shared__ unsigned lw[CH];
    __shared__ unsigned lw2[CH];
    __shared__ int gdst[CH];
    __shared__ short lb[CH];
    __shared__ int s[512];
    __shared__ int cnt[NB];
    __shared__ int lstart[NB];
    int t = threadIdx.x;
    int e0 = blockIdx.x * CH;
    int n = min(CH, N_EDGES - e0);
    for (int i = t; i < NB; i += 512) cnt[i] = 0;
    __syncthreads();
    for (int i = t; i < n; i += 512) {
        int sv = src[e0 + i], d = dst[e0 + i];
        lw[i] = ((unsigned)(d & 255) << 24) | (unsigned)sv;
        int b = d >> 8;
        lb[i] = (short)b;
        atomicAdd(&cnt[b], 1);
    }
    __syncthreads();
    int v = (t < NB) ? cnt[t] : 0;
    s[t] = v;
    __syncthreads();
    for (int off = 1; off < 512; off <<= 1) {
        int u = (t >= off) ? s[t - off] : 0;
        __syncthreads();
        s[t] += u;
        __syncthreads();
    }
    if (t < NB) {
        s[t] -= v;                               // local exclusive offset
        lstart[t] = v ? atomicAdd(&bcur[t], v) : 0;
        cnt[t] = 0;                              // reuse as local cursor
    }
    __syncthreads();
    for (int i = t; i < n; i += 512) {
        int b = lb[i];
        int r = atomicAdd(&cnt[b], 1);
        int sl = s[b] + r;
        lw2[sl] = lw[i];
        gdst[sl] = lstart[b] + r;
    }
    __syncthreads();
    for (int j = t; j < n; j += 512)             // consecutive j -> consecutive dest
        pairs[gdst[j]] = lw2[j];
}

// ---------- bucket-local CSR fill; self-loop at slot 0; NO padding ----------
__global__ __launch_bounds__(256) void csr_fill_bucket(const unsigned* __restrict__ pairs,
                                                       const int* __restrict__ boffs,
                                                       int2* __restrict__ rinfo,
                                                       float* __restrict__ dinv,
                                                       int* __restrict__ srcs) {
    __shared__ int lcnt[256];
    __shared__ int ls[256];
    int t = threadIdx.x, b = blockIdx.x, base = b << 8;
    lcnt[t] = 0;
    __syncthreads();
    int lo_e = boffs[b], hi_e = boffs[b + 1];
    for (int i = lo_e + t; i < hi_e; i += 256)
        atomicAdd(&lcnt[pairs[i] >> 24], 1);
    __syncthreads();
    int c = lcnt[t];
    int len = c + 1;                   // self-loop included, exact length
    ls[t] = len;
    __syncthreads();
    for (int off = 1; off < 256; off <<= 1) {
        int u = (t >= off) ? ls[t - off] : 0;
        __syncthreads();
        ls[t] += u;
        __syncthreads();
    }
    int rp = lo_e + base + ls[t] - len;   // edges-before + selves-before
    int node = base + t;
    if (node < N_NODES) {
        rinfo[node] = make_int2(rp, rp + len);
        dinv[node] = rsqrtf((float)len);
        srcs[rp] = node;               // folded self-loop at slot 0
    }
    __syncthreads();
    lcnt[t] = rp + 1;                  // reuse as global cursor (slot 0 = self)
    __syncthreads();
    for (int i = lo_e + t; i < hi_e; i += 256) {
        unsigned p = pairs[i];
        int li = p >> 24;
        int pos = atomicAdd(&lcnt[li], 1);
        srcs[pos] = (int)(p & 0xFFFFFFu);
    }
}

// ---------- W1 [128][128] + W2 [128][64] fp32 -> Wt [N][128] bf16 ----------
__global__ __launch_bounds__(256) void convert_w(const float* __restrict__ W1,
                                                 const float* __restrict__ W2,
                                                 short* __restrict__ w1h,
                                                 short* __restrict__ w2h) {
    int id = blockIdx.x * 256 + threadIdx.x;
    if (id < 128 * 128) {
        int n = id >> 7, k = id & 127;
        w1h[id] = f2b(W1[k * 128 + n]);
    } else if (id < 128 * 128 + 64 * 128) {
        int j = id - 128 * 128;
        int n = j >> 7, k = j & 127;
        w2h[j] = f2b(W2[k * 64 + n]);
    }
}

// ---------- layer-1 GEMM: Y1 = fp8((X @ W1) * dinv); W in LDS, 16 rows/wave ----------
__global__ __launch_bounds__(512) void gemm1_mfma(const float* __restrict__ X,
                                                  const short* __restrict__ Wt,
                                                  const float* __restrict__ dinv,
                                                  unsigned char* __restrict__ Yf) {
    __shared__ short Ws[128 * 128];   // 32 KB
    const int t = threadIdx.x;
    for (int i = t * 8; i < 128 * 128; i += 512 * 8)
        *(short8*)(Ws + i) = *(const short8*)(Wt + i);
    __syncthreads();

    const int w = t >> 6, lane = t & 63;
    const int m = lane & 15, q = lane >> 4;
    const int r0 = blockIdx.x * 128 + w * 16;
    const int ra = min(r0 + m, N_NODES - 1);

    f32x4 acc[8];
#pragma unroll
    for (int c = 0; c < 8; ++c) acc[c] = (f32x4)(0.f);

#pragma unroll
    for (int kk = 0; kk < 4; ++kk) {
        const int koff = kk * 32 + q * 8;
        short8 a = pack8t(X + (size_t)ra * 128 + koff);
#pragma unroll
        for (int c = 0; c < 8; ++c) {
            short8 bh = *(const short8*)(Ws + (c * 16 + m) * 128 + koff);
            acc[c] = __builtin_amdgcn_mfma_f32_16x16x32_bf16(a, bh, acc[c], 0, 0, 0);
        }
    }

    // C/D layout: col=lane&15, row=q*4+reg  [verified m89/m91]
    const int rb0 = r0 + q * 4;
    f32x4 dv = *(const f32x4*)(dinv + rb0);
#pragma unroll
    for (int c = 0; c < 8; ++c) {
        const int col = c * 16 + m;
#pragma unroll
        for (int r = 0; r < 4; ++r) {
            int row = rb0 + r;
            if (row < N_NODES) Yf[(size_t)row * 128 + col] = f2q(acc[c][r] * dv[r]);
        }
    }
}

// ---------- layer-2 GEMM: Y2 = fp8((H @ W2) * dinv); W in LDS, 16 rows/wave ----------
__global__ __launch_bounds__(512) void gemm2_mfma(const short* __restrict__ H,
                                                  const short* __restrict__ Wt,
                                                  const float* __restrict__ dinv,
                                                  unsigned char* __restrict__ Yf) {
    __shared__ short Ws[64 * 128];    // 16 KB
    const int t = threadIdx.x;
    for (int i = t * 8; i < 64 * 128; i += 512 * 8)
        *(short8*)(Ws + i) = *(const short8*)(Wt + i);
    __syncthreads();

    const int w = t >> 6, lane = t & 63;
    const int m = lane & 15, q = lane >> 4;
    const int r0 = blockIdx.x * 128 + w * 16;

    f32x4 acc[4];
#pragma unroll
    for (int c = 0; c < 4; ++c) acc[c] = (f32x4)(0.f);

#pragma unroll
    for (int kk = 0; kk < 4; ++kk) {
        const int koff = kk * 32 + q * 8;
        short8 a = *(const short8*)(H + (size_t)(r0 + m) * 128 + koff);
#pragma unroll
        for (int c = 0; c < 4; ++c) {
            short8 bh = *(const short8*)(Ws + (c * 16 + m) * 128 + koff);
            acc[c] = __builtin_amdgcn_mfma_f32_16x16x32_bf16(a, bh, acc[c], 0, 0, 0);
        }
    }

    const int rb0 = r0 + q * 4;
    f32x4 dv = *(const f32x4*)(dinv + rb0);
#pragma unroll
    for (int c = 0; c < 4; ++c) {
        const int col = c * 16 + m;
#pragma unroll
        for (int r = 0; r < 4; ++r) {
            int row = rb0 + r;
            if (row < N_NODES) Yf[(size_t)row * 64 + col] = f2q(acc[c][r] * dv[r]);
        }
    }
}

// ---------- CSR aggregation, K=128 fp8: depth-2 predicated (proven optimal) ----------
// 8-lane group owns one node. Every row-gather / srcs load / accumulate is
// predicated on row<len: finished groups issue ZERO memory requests. At the
// compulsory-fetch x ~2.2TB/s fabric floor (86MB / 40us); deeper pipelines and
// reorderings all measured neutral-to-worse (rounds 2-7).
__global__ __launch_bounds__(256) void agg_relu(const int2* __restrict__ rinfo,
                                                const int* __restrict__ srcs,
                                                const unsigned char* __restrict__ Yf,
                                                const float* __restrict__ dinv,
                                                const float* __restrict__ b,
                                                short* __restrict__ Hb) {
    int t = threadIdx.x;
    int lane = t & 63, w = t >> 6;
    int g = lane >> 3, fl = lane & 7;          // 8 groups of 8 lanes
    int node = blockIdx.x * 32 + w * 8 + g;    // N_NODES % 32 == 0
    const unsigned fo = (unsigned)(fl << 4);   // 16B per lane within 128B row
    int2 r = rinfo[node];
    int e = r.x, len = r.y - r.x;              // exact, >= 1 (self)
    int mx = len;                               // wave-max chain length
    mx = max(mx, __shfl_xor(mx, 8));
    mx = max(mx, __shfl_xor(mx, 16));
    mx = max(mx, __shfl_xor(mx, 32));
    f32x2 a[8];
#pragma unroll
    for (int i = 0; i < 8; ++i) a[i] = (f32x2)(0.f);

    uint4 GA0, GA1;
    unsigned sB0 = 0, sB1 = 0;
    {   // prologue: rows 0,1 in flight; srcs for rows 2,3
        unsigned s0 = (unsigned)srcs[e];                       // len>=1 always
        GA0 = *(const uint4*)(Yf + ((s0 << 7) + fo));
        if (1 < len) {
            unsigned s1 = (unsigned)srcs[e + 1];
            GA1 = *(const uint4*)(Yf + ((s1 << 7) + fo));
        }
        if (2 < len) sB0 = (unsigned)srcs[e + 2];
        if (3 < len) sB1 = (unsigned)srcs[e + 3];
    }
    for (int i = 0; i < mx; i += 2) {
        uint4 GB0, GB1;
        if (i + 2 < len) GB0 = *(const uint4*)(Yf + ((sB0 << 7) + fo));
        if (i + 3 < len) GB1 = *(const uint4*)(Yf + ((sB1 << 7) + fo));
        unsigned sC0 = sB0, sC1 = sB1;
        if (i + 4 < len) sC0 = (unsigned)srcs[e + i + 4];
        if (i + 5 < len) sC1 = (unsigned)srcs[e + i + 5];
        if (i < len)     acc16(a, GA0);
        if (i + 1 < len) acc16(a, GA1);
        GA0 = GB0; GA1 = GB1; sB0 = sC0; sB1 = sC1;
    }

    // epilogue: lane holds final features [16*fl, 16*fl+16) of its node
    float sc = dinv[node];
    const float4* bf = (const float4*)b;
    float bb[16];
    *(float4*)(bb + 0)  = bf[fl * 4 + 0];
    *(float4*)(bb + 4)  = bf[fl * 4 + 1];
    *(float4*)(bb + 8)  = bf[fl * 4 + 2];
    *(float4*)(bb + 12) = bf[fl * 4 + 3];
    unsigned u[8];
#pragma unroll
    for (int k = 0; k < 8; ++k) {
        float v0 = fmaxf(sc * a[k][0] + bb[2 * k], 0.f);
        float v1 = fmaxf(sc * a[k][1] + bb[2 * k + 1], 0.f);
        u[k] = pk2(v0, v1);
    }
    uint4* hp = (uint4*)Hb + (size_t)node * 16 + fl * 2;
    hp[0] = make_uint4(u[0], u[1], u[2], u[3]);
    hp[1] = make_uint4(u[4], u[5], u[6], u[7]);
}

// ---------- CSR aggregation, K=64 fp8: depth-2 predicated + log_softmax ----------
__global__ __launch_bounds__(256) void agg_lsm(const int2* __restrict__ rinfo,
                                               const int* __restrict__ srcs,
                                               const unsigned char* __restrict__ Yf,
                                               const float* __restrict__ dinv,
                                               const float* __restrict__ b,
                                               float* __restrict__ out) {
    int t = threadIdx.x;
    int lane = t & 63, w = t >> 6;
    int g = lane >> 2, fl = lane & 3;          // 16 groups of 4 lanes
    int node = blockIdx.x * 64 + w * 16 + g;   // last block partially OOB
    int nd = min(node, N_NODES - 1);
    const unsigned fo = (unsigned)(fl << 4);   // 16B per lane within 64B row
    int2 r = rinfo[nd];
    int e = r.x, len = r.y - r.x;
    int mx = len;
    mx = max(mx, __shfl_xor(mx, 4));
    mx = max(mx, __shfl_xor(mx, 8));
    mx = max(mx, __shfl_xor(mx, 16));
    mx = max(mx, __shfl_xor(mx, 32));
    f32x2 a[8];
#pragma unroll
    for (int i = 0; i < 8; ++i) a[i] = (f32x2)(0.f);

    uint4 GA0, GA1;
    unsigned sB0 = 0, sB1 = 0;
    {
        unsigned s0 = (unsigned)srcs[e];
        GA0 = *(const uint4*)(Yf + ((s0 << 6) + fo));
        if (1 < len) {
            unsigned s1 = (unsigned)srcs[e + 1];
            GA1 = *(const uint4*)(Yf + ((s1 << 6) + fo));
        }
        if (2 < len) sB0 = (unsigned)srcs[e + 2];
        if (3 < len) sB1 = (unsigned)srcs[e + 3];
    }
    for (int i = 0; i < mx; i += 2) {
        uint4 GB0, GB1;
        if (i + 2 < len) GB0 = *(const uint4*)(Yf + ((sB0 << 6) + fo));
        if (i + 3 < len) GB1 = *(const uint4*)(Yf + ((sB1 << 6) + fo));
        unsigned sC0 = sB0, sC1 = sB1;
        if (i + 4 < len) sC0 = (unsigned)srcs[e + i + 4];
        if (i + 5 < len) sC1 = (unsigned)srcs[e + i + 5];
        if (i < len)     acc16(a, GA0);
        if (i + 1 < len) acc16(a, GA1);
        GA0 = GB0; GA1 = GB1; sB0 = sC0; sB1 = sC1;
    }

    // epilogue: lane holds final features [16*fl, 16*fl+16) of its node
    float sc = dinv[nd];
    const float4* bf = (const float4*)b;
    float bb[16];
    *(float4*)(bb + 0)  = bf[fl * 4 + 0];
    *(float4*)(bb + 4)  = bf[fl * 4 + 1];
    *(float4*)(bb + 8)  = bf[fl * 4 + 2];
    *(float4*)(bb + 12) = bf[fl * 4 + 3];
    float v[16];
#pragma unroll
    for (int j = 0; j < 16; ++j) v[j] = sc * a[j >> 1][j & 1] + bb[j];
    float m = v[0];
#pragma unroll
    for (int j = 1; j < 16; ++j) m = fmaxf(m, v[j]);
    m = fmaxf(m, __shfl_xor(m, 1));            // fl = lane bits 0..1
    m = fmaxf(m, __shfl_xor(m, 2));
    float su = 0.f;
#pragma unroll
    for (int j = 0; j < 16; ++j) su += __expf(v[j] - m);
    su += __shfl_xor(su, 1);
    su += __shfl_xor(su, 2);
    float ls = m + logf(su);
    if (node < N_NODES) {
        float4* op = (float4*)out + (size_t)node * 16 + fl * 4;
        op[0] = make_float4(v[0] - ls,  v[1] - ls,  v[2] - ls,  v[3] - ls);
        op[1] = make_float4(v[4] - ls,  v[5] - ls,  v[6] - ls,  v[7] - ls);
        op[2] = make_float4(v[8] - ls,  v[9] - ls,  v[10] - ls, v[11] - ls);
        op[3] = make_float4(v[12] - ls, v[13] - ls, v[14] - ls, v[15] - ls);
    }
}

extern "C" void kernel_launch(void* const* d_in, const int* in_sizes, int n_in,
                              void* d_out, int out_size, void* d_ws, size_t ws_size,
                              hipStream_t stream) {
    const float* x  = (const float*)d_in[0];
    const float* W1 = (const float*)d_in[1];
    const float* b1 = (const float*)d_in[2];
    const float* W2 = (const float*)d_in[3];
    const float* b2 = (const float*)d_in[4];
    const int* edge = (const int*)d_in[5];
    const int* src = edge;
    const int* dst = edge + N_EDGES;
    float* out = (float*)d_out;

    char* ws = (char*)d_ws;
    int*           bcnt  = (int*)(ws + 0);             //     1,564
    int*           boffs = (int*)(ws + 2048);          //     1,568
    int*           bcur  = (int*)(ws + 4096);          //     1,564
    float*         dinv  = (float*)(ws + 6144);        //   400,384 (MROWS)
    int2*          rinfo = (int2*)(ws + 406528);       //   800,000
    int*           srcs  = (int*)(ws + 1206528);       //  6,800,000 (exact CSR, self folded)
    unsigned*      pairs = (unsigned*)(ws + 14012672); //  6,400,000
    short*         w1h   = (short*)(ws + 20412672);    //     32,768
    short*         w2h   = (short*)(ws + 20445440);    //     16,384
    unsigned char* y1f   = (unsigned char*)(ws + 20461824); // 12,812,288 (MROWS*128 fp8)
    short*         h1b   = (short*)(ws + 33274112);    // 25,624,576 (MROWS*128 bf16)
    unsigned char* y2f   = (unsigned char*)(ws + 58898688); //  6,406,144 (MROWS*64 fp8)
    // ends ~65.3 MB

    // ---- init: bcnt zeros ----
    init_misc<<<1, 512, 0, stream>>>(bcnt);

    // ---- CSR build: bucket histogram -> scan -> sorted scatter -> exact bucket fill ----
    bucket_count<<<512, 256, 0, stream>>>(dst, bcnt);
    bucket_scan<<<1, 512, 0, stream>>>(bcnt, boffs, bcur);
    bucket_scatter<<<(N_EDGES + CH - 1) / CH, 512, 0, stream>>>(src, dst, bcur, pairs);
    csr_fill_bucket<<<NB, 256, 0, stream>>>(pairs, boffs, rinfo, dinv, srcs);

    // ---- weight conversion ----
    convert_w<<<(128 * 128 + 64 * 128 + 255) / 256, 256, 0, stream>>>(W1, W2, w1h, w2h);

    // ---- layer 1 ----
    gemm1_mfma<<<MROWS / 128, 512, 0, stream>>>(x, w1h, dinv, y1f);
    agg_relu<<<N_NODES / 32, 256, 0, stream>>>(rinfo, srcs, y1f, dinv, b1, h1b);

    // ---- layer 2 ----
    gemm2_mfma<<<MROWS / 128, 512, 0, stream>>>(h1b, w2h, dinv, y2f);
    agg_lsm<<<(N_NODES + 63) / 64, 256, 0, stream>>>(rinfo, srcs, y2f, dinv, b2, out);
}